// Round 1
// baseline (963.755 us; speedup 1.0000x reference)
//
#include <hip/hip_runtime.h>
#include <math.h>

// Problem constants
#define TT 4
#define BB 16
#define CC 256
#define NN 1024
#define NTILE 16
#define COLS 64   // TT * NTILE
#define EPSF 1e-5f

// 4-step LIF chain, tau=2 hard-reset (v_reset=0), spike = (h - th >= 0).
// Mirrors reference op order: h = v + (x - v)/tau  (div by 2 == *0.5 exact).
__device__ __forceinline__ void lif4(float x0, float x1, float x2, float x3, float th,
                                     float& s0, float& s1, float& s2, float& s3) {
  float v = 0.f, h;
  h = v + (x0 - v) * 0.5f; s0 = (h >= th) ? 1.f : 0.f; v = (h >= th) ? 0.f : h;
  h = v + (x1 - v) * 0.5f; s1 = (h >= th) ? 1.f : 0.f; v = (h >= th) ? 0.f : h;
  h = v + (x2 - v) * 0.5f; s2 = (h >= th) ? 1.f : 0.f; v = (h >= th) ? 0.f : h;
  h = v + (x3 - v) * 0.5f; s3 = (h >= th) ? 1.f : 0.f; v = (h >= th) ? 0.f : h;
}

__global__ __launch_bounds__(256, 2)
void pushpull_fused(const float* __restrict__ x,
                    const float* __restrict__ q_w, const float* __restrict__ q_gamma,
                    const float* __restrict__ q_beta, const float* __restrict__ q_mean,
                    const float* __restrict__ q_var,
                    const float* __restrict__ k_w, const float* __restrict__ k_gamma,
                    const float* __restrict__ k_beta, const float* __restrict__ k_mean,
                    const float* __restrict__ k_var,
                    const float* __restrict__ proj_w, const float* __restrict__ proj_b,
                    const float* __restrict__ p_gamma, const float* __restrict__ p_beta,
                    const float* __restrict__ p_mean, const float* __restrict__ p_var,
                    float* __restrict__ out) {
  // x tile for this (b, n0): xs[c][col], col = t*16 + nl. 64 KB.
  __shared__ float xs[CC][COLS];

  const int tid  = threadIdx.x;
  const int b    = blockIdx.x >> 6;          // 16 batches
  const int n0   = (blockIdx.x & 63) * NTILE; // 64 spatial tiles
  const int lane = tid & 63;
  // readfirstlane: prove wave-uniformity so weight reads scalarize to s_load
  const int wave = __builtin_amdgcn_readfirstlane(tid >> 6);
  const int tl   = lane >> 4;   // this lane's timestep
  const int nl   = lane & 15;   // this lane's spatial offset

  // ---- Stage x tile: [4t][256c][16n] -> xs[c][t*16+n], float4 (64B rows) ----
  for (int s4 = tid; s4 < CC * 16; s4 += 256) {
    const int c  = s4 >> 4;
    const int g  = s4 & 15;
    const int t  = g >> 2;
    const int n4 = (g & 3) * 4;
    const float4 v = *reinterpret_cast<const float4*>(
        x + (((size_t)t * BB + b) * CC + c) * NN + n0 + n4);
    *reinterpret_cast<float4*>(&xs[c][t * 16 + n4]) = v;
  }
  __syncthreads();

  // ---- q & k GEMMs + BN + LIFs. Wave owns channels [wave*64, wave*64+64) ----
  float qe_sum[2] = {0.f, 0.f};
  float qi_sum[2] = {0.f, 0.f};
  unsigned long long ks_mask = 0ull;
  const int obase = wave * 64;

  #pragma unroll 1
  for (int og = 0; og < 8; ++og) {   // 8 channels per group
    float accq[8], acck[8];
    #pragma unroll
    for (int i = 0; i < 8; ++i) { accq[i] = 0.f; acck[i] = 0.f; }
    const float* qwr = q_w + (size_t)(obase + og * 8) * CC;
    const float* kwr = k_w + (size_t)(obase + og * 8) * CC;
    #pragma unroll 4
    for (int c = 0; c < CC; ++c) {
      const float v = xs[c][lane];     // broadcast row, 2-way bank alias (free)
      #pragma unroll
      for (int i = 0; i < 8; ++i) {
        accq[i] = fmaf(qwr[i * CC + c], v, accq[i]);
        acck[i] = fmaf(kwr[i * CC + c], v, acck[i]);
      }
    }
    #pragma unroll
    for (int i = 0; i < 8; ++i) {
      const int o = obase + og * 8 + i;
      const float qinv = q_gamma[o] / sqrtf(q_var[o] + EPSF);
      const float qv = (accq[i] - q_mean[o]) * qinv + q_beta[o];
      const float kinv = k_gamma[o] / sqrtf(k_var[o] + EPSF);
      const float kv = (acck[i] - k_mean[o]) * kinv + k_beta[o];
      // gather this (o, nl)'s values across t
      const float q0 = __shfl(qv, nl),      q1 = __shfl(qv, nl + 16);
      const float q2 = __shfl(qv, nl + 32), q3 = __shfl(qv, nl + 48);
      const float k0 = __shfl(kv, nl),      k1 = __shfl(kv, nl + 16);
      const float k2 = __shfl(kv, nl + 32), k3 = __shfl(kv, nl + 48);
      float s0, s1, s2, s3;
      lif4(q0, q1, q2, q3, 1.0f, s0, s1, s2, s3);
      const float se = tl == 0 ? s0 : tl == 1 ? s1 : tl == 2 ? s2 : s3;
      lif4(-q0, -q1, -q2, -q3, 1.0f, s0, s1, s2, s3);
      const float si = tl == 0 ? s0 : tl == 1 ? s1 : tl == 2 ? s2 : s3;
      lif4(k0, k1, k2, k3, 1.0f, s0, s1, s2, s3);
      const float sk = tl == 0 ? s0 : tl == 1 ? s1 : tl == 2 ? s2 : s3;
      const int hd = og >> 2;            // 2 heads per wave (32 ch each)
      qe_sum[hd] += se;
      qi_sum[hd] += si;
      ks_mask |= ((unsigned long long)(sk != 0.f)) << (og * 8 + i);
    }
  }

  // ---- attention gate per head: lif(qe_sum - qi_sum, th=0.5), exact ints ----
  float attn[2];
  #pragma unroll
  for (int hd = 0; hd < 2; ++hd) {
    const float a = qe_sum[hd] - qi_sum[hd];
    const float a0 = __shfl(a, nl),      a1 = __shfl(a, nl + 16);
    const float a2 = __shfl(a, nl + 32), a3 = __shfl(a, nl + 48);
    float s0, s1, s2, s3;
    lif4(a0, a1, a2, a3, 0.5f, s0, s1, s2, s3);
    attn[hd] = tl == 0 ? s0 : tl == 1 ? s1 : tl == 2 ? s2 : s3;
  }

  __syncthreads();  // all waves done reading xs
  // ---- x_one = attn * k_s  (binary), overwrite xs in place ----
  #pragma unroll 1
  for (int ol = 0; ol < 64; ++ol) {
    const float xv = ((ks_mask >> ol) & 1ull) ? attn[ol >> 5] : 0.f;
    xs[obase + ol][lane] = xv;
  }
  __syncthreads();

  // ---- proj GEMM + bias + BN + final LIF + store ----
  #pragma unroll 1
  for (int og = 0; og < 4; ++og) {   // 16 channels per group
    float acc[16];
    #pragma unroll
    for (int i = 0; i < 16; ++i) acc[i] = 0.f;
    const float* pwr = proj_w + (size_t)(obase + og * 16) * CC;
    #pragma unroll 4
    for (int c = 0; c < CC; ++c) {
      const float v = xs[c][lane];
      #pragma unroll
      for (int i = 0; i < 16; ++i) acc[i] = fmaf(pwr[i * CC + c], v, acc[i]);
    }
    #pragma unroll
    for (int i = 0; i < 16; ++i) {
      const int o = obase + og * 16 + i;
      const float pv0 = acc[i] + proj_b[o];
      const float pinv = p_gamma[o] / sqrtf(p_var[o] + EPSF);
      const float pv = (pv0 - p_mean[o]) * pinv + p_beta[o];
      const float p0 = __shfl(pv, nl),      p1 = __shfl(pv, nl + 16);
      const float p2 = __shfl(pv, nl + 32), p3 = __shfl(pv, nl + 48);
      float s0, s1, s2, s3;
      lif4(p0, p1, p2, p3, 1.0f, s0, s1, s2, s3);
      const float sp = tl == 0 ? s0 : tl == 1 ? s1 : tl == 2 ? s2 : s3;
      out[(((size_t)tl * BB + b) * CC + o) * NN + n0 + nl] = sp;
    }
  }
}

extern "C" void kernel_launch(void* const* d_in, const int* in_sizes, int n_in,
                              void* d_out, int out_size, void* d_ws, size_t ws_size,
                              hipStream_t stream) {
  const float* x       = (const float*)d_in[0];
  const float* q_w     = (const float*)d_in[1];
  const float* q_gamma = (const float*)d_in[2];
  const float* q_beta  = (const float*)d_in[3];
  const float* q_mean  = (const float*)d_in[4];
  const float* q_var   = (const float*)d_in[5];
  const float* k_w     = (const float*)d_in[6];
  const float* k_gamma = (const float*)d_in[7];
  const float* k_beta  = (const float*)d_in[8];
  const float* k_mean  = (const float*)d_in[9];
  const float* k_var   = (const float*)d_in[10];
  const float* proj_w  = (const float*)d_in[11];
  const float* proj_b  = (const float*)d_in[12];
  const float* p_gamma = (const float*)d_in[13];
  const float* p_beta  = (const float*)d_in[14];
  const float* p_mean  = (const float*)d_in[15];
  const float* p_var   = (const float*)d_in[16];
  float* out = (float*)d_out;

  dim3 grid(BB * (NN / NTILE));   // 16 * 64 = 1024 blocks
  dim3 block(256);
  pushpull_fused<<<grid, block, 0, stream>>>(
      x, q_w, q_gamma, q_beta, q_mean, q_var,
      k_w, k_gamma, k_beta, k_mean, k_var,
      proj_w, proj_b, p_gamma, p_beta, p_mean, p_var, out);
}

// Round 2
// 580.194 us; speedup vs baseline: 1.6611x; 1.6611x over previous
//
#include <hip/hip_runtime.h>
#include <math.h>

// Problem constants
#define TT 4
#define BB 16
#define CC 256
#define NN 1024
#define NT 8        // spatial positions per block
#define COLS 32     // 4 t * 8 n
#define EPSF 1e-5f

// 4-step LIF chain, tau=2 hard-reset (v_reset=0), spike = (h >= th).
// h = v + (x - v)/2 exactly as reference (div by 2 == *0.5, exact).
__device__ __forceinline__ void lif4(const float xin[4], float th, float s[4]) {
  float v = 0.f;
  #pragma unroll
  for (int t = 0; t < 4; ++t) {
    const float h = v + (xin[t] - v) * 0.5f;
    const bool f = (h >= th);
    s[t] = f ? 1.f : 0.f;
    v = f ? 0.f : h;
  }
}

__device__ __forceinline__ void load8(const float* __restrict__ p, int obase, float v[8]) {
  *reinterpret_cast<float4*>(&v[0]) = *reinterpret_cast<const float4*>(p + obase);
  *reinterpret_cast<float4*>(&v[4]) = *reinterpret_cast<const float4*>(p + obase + 4);
}

// One 256x32 GEMM pass: acc[i][t] = sum_c w[obase+i][c] * xs[c][t*8+nl].
// Weights per-lane via dwordx4 (L1-hot, vmcnt-pipelined); x via LDS b32
// broadcast reads (lgkmcnt counts only LDS -> fine-grained waits).
// FMA order over c is ascending, identical to round-1 (bit-exact numerics).
__device__ __forceinline__ void gemm_pass(const float* __restrict__ w, const float* xs,
                                          int obase, int nl, float acc[8][4]) {
  #pragma unroll
  for (int i = 0; i < 8; ++i)
    #pragma unroll
    for (int t = 0; t < 4; ++t) acc[i][t] = 0.f;

  for (int cq = 0; cq < CC / 4; ++cq) {
    const int c0 = cq * 4;
    float4 wf[8];
    #pragma unroll
    for (int i = 0; i < 8; ++i)
      wf[i] = *reinterpret_cast<const float4*>(w + (size_t)(obase + i) * CC + c0);
    float xf[4][4];
    #pragma unroll
    for (int j = 0; j < 4; ++j)
      #pragma unroll
      for (int t = 0; t < 4; ++t)
        xf[j][t] = xs[(c0 + j) * COLS + t * 8 + nl];
    #pragma unroll
    for (int i = 0; i < 8; ++i) {
      #pragma unroll
      for (int t = 0; t < 4; ++t) {
        float a = acc[i][t];
        a = fmaf(wf[i].x, xf[0][t], a);
        a = fmaf(wf[i].y, xf[1][t], a);
        a = fmaf(wf[i].z, xf[2][t], a);
        a = fmaf(wf[i].w, xf[3][t], a);
        acc[i][t] = a;
      }
    }
  }
}

__global__ __launch_bounds__(256, 4)
void pushpull_fused2(const float* __restrict__ x,
                     const float* __restrict__ q_w, const float* __restrict__ q_gamma,
                     const float* __restrict__ q_beta, const float* __restrict__ q_mean,
                     const float* __restrict__ q_var,
                     const float* __restrict__ k_w, const float* __restrict__ k_gamma,
                     const float* __restrict__ k_beta, const float* __restrict__ k_mean,
                     const float* __restrict__ k_var,
                     const float* __restrict__ proj_w, const float* __restrict__ proj_b,
                     const float* __restrict__ p_gamma, const float* __restrict__ p_beta,
                     const float* __restrict__ p_mean, const float* __restrict__ p_var,
                     float* __restrict__ out) {
  __shared__ float xs[CC * COLS];   // 32 KB: xs[c][t*8+n]

  const int tid   = threadIdx.x;
  const int b     = blockIdx.x >> 7;            // 16 batches
  const int n0    = (blockIdx.x & 127) * NT;    // 128 spatial tiles of 8
  const int oblk  = tid >> 3;                   // 32 o-blocks of 8 channels
  const int nl    = tid & 7;                    // spatial index in tile
  const int obase = oblk * 8;

  // ---- Stage x tile [256c][4t][8n] as float2 (conflict-light, 32B segs) ----
  #pragma unroll
  for (int rep = 0; rep < 16; ++rep) {
    const int f2 = rep * 256 + tid;     // float2 index in [0,4096)
    const int r  = f2 >> 2;             // row = c*4 + t
    const int n2 = (f2 & 3) * 2;
    const int c  = r >> 2;
    const int t  = r & 3;
    const float2 v = *reinterpret_cast<const float2*>(
        x + (((size_t)t * BB + b) * CC + c) * NN + n0 + n2);
    *reinterpret_cast<float2*>(&xs[c * COLS + t * 8 + n2]) = v;
  }
  __syncthreads();

  float d[4] = {0.f, 0.f, 0.f, 0.f};

  // ---- q pass: GEMM + BN + push/pull LIF -> d[t] partial head sums ----
  {
    float acc[8][4];
    gemm_pass(q_w, xs, obase, nl, acc);
    float g[8], be[8], mn[8], vr[8];
    load8(q_gamma, obase, g);  load8(q_beta, obase, be);
    load8(q_mean,  obase, mn); load8(q_var,  obase, vr);
    #pragma unroll
    for (int i = 0; i < 8; ++i) {
      const float inv = g[i] / sqrtf(vr[i] + EPSF);
      float qv[4], nqv[4], se[4], si[4];
      #pragma unroll
      for (int t = 0; t < 4; ++t) {
        qv[t]  = (acc[i][t] - mn[i]) * inv + be[i];
        nqv[t] = -qv[t];
      }
      lif4(qv,  1.0f, se);
      lif4(nqv, 1.0f, si);
      #pragma unroll
      for (int t = 0; t < 4; ++t) d[t] += se[t] - si[t];   // exact small ints
    }
  }

  // ---- k pass: GEMM + BN + LIF -> binary mask ----
  unsigned kmask = 0u;
  {
    float acc[8][4];
    gemm_pass(k_w, xs, obase, nl, acc);
    float g[8], be[8], mn[8], vr[8];
    load8(k_gamma, obase, g);  load8(k_beta, obase, be);
    load8(k_mean,  obase, mn); load8(k_var,  obase, vr);
    #pragma unroll
    for (int i = 0; i < 8; ++i) {
      const float inv = g[i] / sqrtf(vr[i] + EPSF);
      float kv[4], sk[4];
      #pragma unroll
      for (int t = 0; t < 4; ++t) kv[t] = (acc[i][t] - mn[i]) * inv + be[i];
      lif4(kv, 1.0f, sk);
      #pragma unroll
      for (int t = 0; t < 4; ++t)
        kmask |= (sk[t] != 0.f) ? (1u << (i * 4 + t)) : 0u;
    }
  }

  // ---- head reduce (4 oblks = 32 ch per head) + attention LIF gate ----
  float at[4];
  {
    #pragma unroll
    for (int t = 0; t < 4; ++t) {
      float v = d[t];
      v += __shfl_xor(v, 8);    // oblk bit0
      v += __shfl_xor(v, 16);   // oblk bit1
      d[t] = v;                 // exact integer sums
    }
    lif4(d, 0.5f, at);
  }

  __syncthreads();  // all xs reads for q/k done
  // ---- x_one = attn & k_s (binary), overwrite xs in place ----
  #pragma unroll
  for (int i = 0; i < 8; ++i)
    #pragma unroll
    for (int t = 0; t < 4; ++t)
      xs[(obase + i) * COLS + t * 8 + nl] = ((kmask >> (i * 4 + t)) & 1u) ? at[t] : 0.f;
  __syncthreads();

  // ---- proj pass: GEMM + bias + BN + final LIF + store ----
  {
    float acc[8][4];
    gemm_pass(proj_w, xs, obase, nl, acc);
    float g[8], be[8], mn[8], vr[8], pb[8];
    load8(p_gamma, obase, g);  load8(p_beta, obase, be);
    load8(p_mean,  obase, mn); load8(p_var,  obase, vr);
    load8(proj_b,  obase, pb);
    #pragma unroll
    for (int i = 0; i < 8; ++i) {
      const float inv = g[i] / sqrtf(vr[i] + EPSF);
      float pv[4], sp[4];
      #pragma unroll
      for (int t = 0; t < 4; ++t)
        pv[t] = ((acc[i][t] + pb[i]) - mn[i]) * inv + be[i];
      lif4(pv, 1.0f, sp);
      #pragma unroll
      for (int t = 0; t < 4; ++t)
        out[(((size_t)t * BB + b) * CC + obase + i) * NN + n0 + nl] = sp[t];
    }
  }
}

extern "C" void kernel_launch(void* const* d_in, const int* in_sizes, int n_in,
                              void* d_out, int out_size, void* d_ws, size_t ws_size,
                              hipStream_t stream) {
  const float* x       = (const float*)d_in[0];
  const float* q_w     = (const float*)d_in[1];
  const float* q_gamma = (const float*)d_in[2];
  const float* q_beta  = (const float*)d_in[3];
  const float* q_mean  = (const float*)d_in[4];
  const float* q_var   = (const float*)d_in[5];
  const float* k_w     = (const float*)d_in[6];
  const float* k_gamma = (const float*)d_in[7];
  const float* k_beta  = (const float*)d_in[8];
  const float* k_mean  = (const float*)d_in[9];
  const float* k_var   = (const float*)d_in[10];
  const float* proj_w  = (const float*)d_in[11];
  const float* proj_b  = (const float*)d_in[12];
  const float* p_gamma = (const float*)d_in[13];
  const float* p_beta  = (const float*)d_in[14];
  const float* p_mean  = (const float*)d_in[15];
  const float* p_var   = (const float*)d_in[16];
  float* out = (float*)d_out;

  dim3 grid(BB * (NN / NT));   // 16 * 128 = 2048 blocks
  dim3 block(256);
  pushpull_fused2<<<grid, block, 0, stream>>>(
      x, q_w, q_gamma, q_beta, q_mean, q_var,
      k_w, k_gamma, k_beta, k_mean, k_var,
      proj_w, proj_b, p_gamma, p_beta, p_mean, p_var, out);
}

// Round 3
// 573.005 us; speedup vs baseline: 1.6819x; 1.0125x over previous
//
#include <hip/hip_runtime.h>
#include <math.h>

// Problem constants
#define TT 4
#define BB 16
#define CC 256
#define NN 1024
#define NT 8        // spatial positions per block
#define COLS 32     // 8 n * 4 t  (layout: xs[c][n][t], t contiguous)
#define EPSF 1e-5f

#define XS(c, n, t) xs[((c) * NT + (n)) * TT + (t)]

// 4-step LIF chain, tau=2 hard-reset (v_reset=0), spike = (h >= th).
// h = v + (x - v)/2 exactly as reference (div by 2 == *0.5, exact).
__device__ __forceinline__ void lif4(const float xin[4], float th, float s[4]) {
  float v = 0.f;
  #pragma unroll
  for (int t = 0; t < 4; ++t) {
    const float h = v + (xin[t] - v) * 0.5f;
    const bool f = (h >= th);
    s[t] = f ? 1.f : 0.f;
    v = f ? 0.f : h;
  }
}

__device__ __forceinline__ void load8(const float* __restrict__ p, int obase, float v[8]) {
  *reinterpret_cast<float4*>(&v[0]) = *reinterpret_cast<const float4*>(p + obase);
  *reinterpret_cast<float4*>(&v[4]) = *reinterpret_cast<const float4*>(p + obase + 4);
}

__device__ __forceinline__ void fma4(float4& a, float s, const float4& v) {
  a.x = fmaf(s, v.x, a.x);
  a.y = fmaf(s, v.y, a.y);
  a.z = fmaf(s, v.z, a.z);
  a.w = fmaf(s, v.w, a.w);
}

// One 256x32 GEMM pass: acc[i].{x..w} = sum_c w[obase+i][c] * xs[c][nl][t].
// Weights per-lane dwordx4 (L1-hot, 8-way same-address merge in TA);
// x via ds_read_b128 (4 t-values per read, conflict-free broadcast).
// FMA order over c ascending (j inner over quad, cq outer) == rounds 1/2
// bit-exactly; dependent updates to one acc are 32 instructions apart.
__device__ __forceinline__ void gemm_pass(const float* __restrict__ w, const float* xs,
                                          int obase, int nl, float4 acc[8]) {
  #pragma unroll
  for (int i = 0; i < 8; ++i) acc[i] = make_float4(0.f, 0.f, 0.f, 0.f);

  #pragma unroll 2
  for (int cq = 0; cq < CC / 4; ++cq) {
    const int c0 = cq * 4;
    float4 wf[8];
    #pragma unroll
    for (int i = 0; i < 8; ++i)
      wf[i] = *reinterpret_cast<const float4*>(w + (size_t)(obase + i) * CC + c0);
    float4 xf[4];
    #pragma unroll
    for (int j = 0; j < 4; ++j)
      xf[j] = *reinterpret_cast<const float4*>(&xs[((c0 + j) * NT + nl) * TT]);
    #pragma unroll
    for (int i = 0; i < 8; ++i) fma4(acc[i], wf[i].x, xf[0]);
    #pragma unroll
    for (int i = 0; i < 8; ++i) fma4(acc[i], wf[i].y, xf[1]);
    #pragma unroll
    for (int i = 0; i < 8; ++i) fma4(acc[i], wf[i].z, xf[2]);
    #pragma unroll
    for (int i = 0; i < 8; ++i) fma4(acc[i], wf[i].w, xf[3]);
  }
}

__global__ __launch_bounds__(256, 4)
void pushpull_fused3(const float* __restrict__ x,
                     const float* __restrict__ q_w, const float* __restrict__ q_gamma,
                     const float* __restrict__ q_beta, const float* __restrict__ q_mean,
                     const float* __restrict__ q_var,
                     const float* __restrict__ k_w, const float* __restrict__ k_gamma,
                     const float* __restrict__ k_beta, const float* __restrict__ k_mean,
                     const float* __restrict__ k_var,
                     const float* __restrict__ proj_w, const float* __restrict__ proj_b,
                     const float* __restrict__ p_gamma, const float* __restrict__ p_beta,
                     const float* __restrict__ p_mean, const float* __restrict__ p_var,
                     float* __restrict__ out) {
  __shared__ float xs[CC * COLS];   // 32 KB: xs[c][n][t]

  const int tid   = threadIdx.x;
  const int b     = blockIdx.x >> 7;            // 16 batches
  const int n0    = (blockIdx.x & 127) * NT;    // 128 spatial tiles of 8
  const int oblk  = tid >> 3;                   // 32 o-blocks of 8 channels
  const int nl    = tid & 7;                    // spatial index in tile
  const int obase = oblk * 8;

  // ---- Stage x tile: float4 global reads -> scalar LDS writes [c][n][t] ----
  // idx4: n4=(idx4&1)*4, t=(idx4>>1)&3, c=idx4>>3. Banks 2-way aliased (free).
  #pragma unroll
  for (int rep = 0; rep < 8; ++rep) {
    const int idx4 = rep * 256 + tid;
    const int n4 = (idx4 & 1) * 4;
    const int t  = (idx4 >> 1) & 3;
    const int c  = idx4 >> 3;
    const float4 v = *reinterpret_cast<const float4*>(
        x + (((size_t)t * BB + b) * CC + c) * NN + n0 + n4);
    XS(c, n4 + 0, t) = v.x;
    XS(c, n4 + 1, t) = v.y;
    XS(c, n4 + 2, t) = v.z;
    XS(c, n4 + 3, t) = v.w;
  }
  __syncthreads();

  float d[4] = {0.f, 0.f, 0.f, 0.f};

  // ---- q pass: GEMM + BN + push/pull LIF -> d[t] partial head sums ----
  {
    float4 acc[8];
    gemm_pass(q_w, xs, obase, nl, acc);
    float g[8], be[8], mn[8], vr[8];
    load8(q_gamma, obase, g);  load8(q_beta, obase, be);
    load8(q_mean,  obase, mn); load8(q_var,  obase, vr);
    #pragma unroll
    for (int i = 0; i < 8; ++i) {
      const float inv = g[i] / sqrtf(vr[i] + EPSF);
      const float* a = &acc[i].x;
      float qv[4], nqv[4], se[4], si[4];
      #pragma unroll
      for (int t = 0; t < 4; ++t) {
        qv[t]  = (a[t] - mn[i]) * inv + be[i];
        nqv[t] = -qv[t];
      }
      lif4(qv,  1.0f, se);
      lif4(nqv, 1.0f, si);
      #pragma unroll
      for (int t = 0; t < 4; ++t) d[t] += se[t] - si[t];   // exact small ints
    }
  }

  // ---- k pass: GEMM + BN + LIF -> binary mask ----
  unsigned kmask = 0u;
  {
    float4 acc[8];
    gemm_pass(k_w, xs, obase, nl, acc);
    float g[8], be[8], mn[8], vr[8];
    load8(k_gamma, obase, g);  load8(k_beta, obase, be);
    load8(k_mean,  obase, mn); load8(k_var,  obase, vr);
    #pragma unroll
    for (int i = 0; i < 8; ++i) {
      const float inv = g[i] / sqrtf(vr[i] + EPSF);
      const float* a = &acc[i].x;
      float kv[4], sk[4];
      #pragma unroll
      for (int t = 0; t < 4; ++t) kv[t] = (a[t] - mn[i]) * inv + be[i];
      lif4(kv, 1.0f, sk);
      #pragma unroll
      for (int t = 0; t < 4; ++t)
        kmask |= (sk[t] != 0.f) ? (1u << (i * 4 + t)) : 0u;
    }
  }

  // ---- head reduce (4 oblks = 32 ch per head) + attention LIF gate ----
  float at[4];
  {
    #pragma unroll
    for (int t = 0; t < 4; ++t) {
      float v = d[t];
      v += __shfl_xor(v, 8);    // oblk bit0
      v += __shfl_xor(v, 16);   // oblk bit1
      d[t] = v;                 // exact integer sums
    }
    lif4(d, 0.5f, at);
  }

  __syncthreads();  // all xs reads for q/k done
  // ---- x_one = attn & k_s (binary), overwrite xs in place (b128 writes) ----
  #pragma unroll
  for (int i = 0; i < 8; ++i) {
    float4 v;
    v.x = ((kmask >> (i * 4 + 0)) & 1u) ? at[0] : 0.f;
    v.y = ((kmask >> (i * 4 + 1)) & 1u) ? at[1] : 0.f;
    v.z = ((kmask >> (i * 4 + 2)) & 1u) ? at[2] : 0.f;
    v.w = ((kmask >> (i * 4 + 3)) & 1u) ? at[3] : 0.f;
    *reinterpret_cast<float4*>(&XS(obase + i, nl, 0)) = v;
  }
  __syncthreads();

  // ---- proj pass: GEMM + bias + BN + final LIF + store ----
  {
    float4 acc[8];
    gemm_pass(proj_w, xs, obase, nl, acc);
    float g[8], be[8], mn[8], vr[8], pb[8];
    load8(p_gamma, obase, g);  load8(p_beta, obase, be);
    load8(p_mean,  obase, mn); load8(p_var,  obase, vr);
    load8(proj_b,  obase, pb);
    #pragma unroll
    for (int i = 0; i < 8; ++i) {
      const float inv = g[i] / sqrtf(vr[i] + EPSF);
      const float* a = &acc[i].x;
      float pv[4], sp[4];
      #pragma unroll
      for (int t = 0; t < 4; ++t)
        pv[t] = ((a[t] + pb[i]) - mn[i]) * inv + be[i];
      lif4(pv, 1.0f, sp);
      #pragma unroll
      for (int t = 0; t < 4; ++t)
        out[(((size_t)t * BB + b) * CC + obase + i) * NN + n0 + nl] = sp[t];
    }
  }
}

extern "C" void kernel_launch(void* const* d_in, const int* in_sizes, int n_in,
                              void* d_out, int out_size, void* d_ws, size_t ws_size,
                              hipStream_t stream) {
  const float* x       = (const float*)d_in[0];
  const float* q_w     = (const float*)d_in[1];
  const float* q_gamma = (const float*)d_in[2];
  const float* q_beta  = (const float*)d_in[3];
  const float* q_mean  = (const float*)d_in[4];
  const float* q_var   = (const float*)d_in[5];
  const float* k_w     = (const float*)d_in[6];
  const float* k_gamma = (const float*)d_in[7];
  const float* k_beta  = (const float*)d_in[8];
  const float* k_mean  = (const float*)d_in[9];
  const float* k_var   = (const float*)d_in[10];
  const float* proj_w  = (const float*)d_in[11];
  const float* proj_b  = (const float*)d_in[12];
  const float* p_gamma = (const float*)d_in[13];
  const float* p_beta  = (const float*)d_in[14];
  const float* p_mean  = (const float*)d_in[15];
  const float* p_var   = (const float*)d_in[16];
  float* out = (float*)d_out;

  dim3 grid(BB * (NN / NT));   // 16 * 128 = 2048 blocks
  dim3 block(256);
  pushpull_fused3<<<grid, block, 0, stream>>>(
      x, q_w, q_gamma, q_beta, q_mean, q_var,
      k_w, k_gamma, k_beta, k_mean, k_var,
      proj_w, proj_b, p_gamma, p_beta, p_mean, p_var, out);
}